// Round 7
// baseline (2957.343 us; speedup 1.0000x reference)
//
#include <hip/hip_runtime.h>
#include <cstdint>
#include <cstddef>

// Problem constants (fixed by the reference)
#define T_STEPS 256
#define BATCH   256
#define DIN     512
#define HID     1024
#define KTOT    1536   // DIN + HID
#define NOUT    4096   // 4*HID
#define BHSZ    ((size_t)BATCH * HID)   // 262144 elems

typedef __bf16 bf16;
typedef __bf16 bf16x4 __attribute__((ext_vector_type(4)));
typedef __bf16 bf16x8 __attribute__((ext_vector_type(8)));
typedef float  f32x4  __attribute__((ext_vector_type(4)));

// cross-XCD-visible bf16 store (write-through to MALL)
__device__ __forceinline__ void store_bf16_sc(bf16* p, bf16 v) {
  unsigned short u = __builtin_bit_cast(unsigned short, v);
  asm volatile("global_store_short %0, %1, off sc0 sc1" :: "v"(p), "v"(u) : "memory");
}

// counted vmcnt wait + scheduler fence (rule #18). Two-level for stringize.
#define VMW_(N) asm volatile("s_waitcnt vmcnt(" #N ")" ::: "memory")
#define VMW(N) do { VMW_(N); __builtin_amdgcn_sched_barrier(0); } while (0)
#define SBAR() __builtin_amdgcn_sched_barrier(0)

// ---------------------------------------------------------------------------
// Gate-interleaved transposed weights: Wt[(j>>4)*64 + gate*16 + (j&15)][k]
__global__ void convert_w_kernel(const float* __restrict__ Wf, const float* __restrict__ Wi,
                                 const float* __restrict__ Wg, const float* __restrict__ Wo,
                                 bf16* __restrict__ Wt) {
  __shared__ float tile[64][17];
  const int k0 = blockIdx.x * 64;
  const int jb = blockIdx.y;
  const int j0 = jb * 16;
  const int t  = threadIdx.x;
  const float* srcs[4] = {Wf, Wi, Wg, Wo};
#pragma unroll
  for (int g = 0; g < 4; ++g) {
    const float* src = srcs[g];
    {
      const int jl = t & 15, kb = t >> 4;
#pragma unroll
      for (int r = 0; r < 4; ++r) {
        const int kl = kb + 16 * r;
        tile[kl][jl] = src[(size_t)(k0 + kl) * HID + (j0 + jl)];
      }
    }
    __syncthreads();
    {
      const int kk = t & 63, jl4 = t >> 6;
#pragma unroll
      for (int r = 0; r < 4; ++r) {
        const int jl = jl4 + 4 * r;
        Wt[(size_t)(jb * 64 + g * 16 + jl) * KTOT + (k0 + kk)] = (bf16)tile[kk][jl];
      }
    }
    __syncthreads();
  }
}

// fp32 -> bf16 convert of X (big-ws path)
__global__ void convert_x_kernel(const float* __restrict__ X, bf16* __restrict__ xb) {
  const int t = blockIdx.y;
  const int i = blockIdx.x * blockDim.x + threadIdx.x;
  const float4 v = ((const float4*)(X + (size_t)t * BATCH * DIN))[i];
  bf16x4 o;
  o[0] = (bf16)v.x; o[1] = (bf16)v.y; o[2] = (bf16)v.z; o[3] = (bf16)v.w;
  ((bf16x4*)(xb + (size_t)t * BATCH * DIN))[i] = o;
}

// ---------------------------------------------------------------------------
// Persistent LSTM v6: B-in-registers + batched h-prefetch + wave0 poll.
// 256 blocks (1/CU) x 512 threads (8 waves). Block: 64 batch x 64 Wt rows.
// Wave: full 64x64 output x K-eighth (6 interleaved 32-k slices ks=wid+8s).
// Steady-state per-wave VMEM queue discipline (oldest-first vmcnt, m135):
//   tail(t-1): stores(4) -> x0,x1 loads(8) -> vmcnt(8) -> flag byte(1)
//   step t   : vmcnt(5)->MFMA x0 ; vmcnt(1)->MFMA x1 ; [wave0 poll] s_barrier
//              issue h2..h5 (16) ; vmcnt(12/8/4/0) -> MFMA h2..h5
//              dump -> syncthreads -> owner-reduce -> gates -> tail(t)
// Flags: u64 per (step, block); producer wave w sets byte w after its stores
// are MALL-acked; consumer wave0 polls the 64 words of its mblk group.
__global__ __launch_bounds__(512, 2)
void lstm_v6(const bf16* __restrict__ Bt,
             const bf16* __restrict__ xb,
             bf16* __restrict__ hseq,
             const bf16* __restrict__ zb16,     // >= 1MB zeros
             float* __restrict__ outF,
             const float* __restrict__ bf_, const float* __restrict__ bi_,
             const float* __restrict__ bg_, const float* __restrict__ bo_,
             unsigned long long* __restrict__ flags64,  // [T][256], zeroed
             float* __restrict__ cxws) {
  __shared__ f32x4 redu[8][16][64];   // 128 KiB -> 1 block/CU

  const int tid = threadIdx.x, lane = tid & 63, wid = tid >> 6;
  const int bid = blockIdx.x;
  const int xcd = bid & 7, sl = bid >> 3;
  const int nblk = xcd * 8 + (sl & 7);
  const int mblk = sl >> 3;
  const int bm0 = mblk * 64;
  const int bn0 = nblk * 64;
  const int fr = lane & 15, fq = lane >> 4;

  // once-per-launch agent acquire: invalidate stale L2 lines (graph replays)
  if (tid == 0)
    (void)__hip_atomic_load((unsigned*)flags64, __ATOMIC_ACQUIRE,
                            __HIP_MEMORY_SCOPE_AGENT);
  __syncthreads();

  const int j = nblk * 16 + fr;
  const float bfv = bf_[j], biv = bi_[j], bgv = bg_[j], bov = bo_[j];
  float cr[2] = {0.f, 0.f};

  // ---- B panel -> registers, once (96 VGPR/lane)
  bf16x8 breg[6][4];
#pragma unroll
  for (int s = 0; s < 6; ++s) {
    const int ks = wid + 8 * s;
#pragma unroll
    for (int nf = 0; nf < 4; ++nf)
      breg[s][nf] = *(const bf16x8*)(Bt + (size_t)(bn0 + nf * 16 + fr) * KTOT
                                     + ks * 32 + fq * 8);
  }

  // 4 rotating A slots (named arrays -> static regalloc)
  bf16x8 sA[4], sB[4], sC[4], sD[4];

  auto ldx = [&](int t2, int s, bf16x8 (&slot)[4]) {   // s in {0,1}
    const bf16* src = xb + (size_t)t2 * BATCH * DIN + (wid + 8 * s) * 32 + fq * 8;
#pragma unroll
    for (int mf = 0; mf < 4; ++mf)
      slot[mf] = *(const bf16x8*)(src + (size_t)(bm0 + mf * 16 + fr) * DIN);
  };
  auto ldh = [&](int t2, int s, bf16x8 (&slot)[4]) {   // s in {2..5}
    const bf16* base = (t2 == 0) ? zb16 : hseq + (size_t)(t2 - 1) * BHSZ;
    const bf16* src = base + (wid + 8 * s) * 32 - 512 + fq * 8;
#pragma unroll
    for (int mf = 0; mf < 4; ++mf)
      slot[mf] = *(const bf16x8*)(src + (size_t)(bm0 + mf * 16 + fr) * HID);
  };

  auto pollf = [&](int tprev) {   // wave0 only
    const unsigned long long* f = flags64 + (size_t)tprev * 256 + mblk * 64;
    const unsigned long long tgt = 0x0101010101010101ULL;
    const unsigned long long tt0 = __builtin_amdgcn_s_memrealtime();
    for (;;) {
      unsigned long long v = __hip_atomic_load(f + lane, __ATOMIC_RELAXED,
                                               __HIP_MEMORY_SCOPE_AGENT);
      if (__all(v == tgt)) break;
      __builtin_amdgcn_s_sleep(1);
      if (__builtin_amdgcn_s_memrealtime() - tt0 > (1ULL << 22)) break;  // fail-soft
    }
    asm volatile("" ::: "memory");
    __builtin_amdgcn_sched_barrier(0);
  };

  // dump + owner-reduce + gates + stores (round-5-proven math)
  auto finish = [&](int t2, f32x4 (&acc)[4][4]) {
#pragma unroll
    for (int mf = 0; mf < 4; ++mf)
#pragma unroll
      for (int nf = 0; nf < 4; ++nf)
        redu[wid][mf * 4 + nf][lane] = acc[mf][nf];
    __syncthreads();
    const int fbase = (wid >> 1) * 4;
    const int rh = wid & 1;
    float z[2][4];
#pragma unroll
    for (int e = 0; e < 2; ++e) {
      const int rloc = rh * 8 + fq * 2 + e;
      const int lsel = (rloc >> 2) * 16 + fr;
      const int rc = rloc & 3;
#pragma unroll
      for (int nf = 0; nf < 4; ++nf) {
        float sum = 0.f;
#pragma unroll
        for (int s = 0; s < 8; ++s)
          sum += ((const float*)&redu[s][fbase + nf][lsel])[rc];
        z[e][nf] = sum;
      }
    }
    float* outSl = outF + (size_t)t2 * BHSZ;
#pragma unroll
    for (int e = 0; e < 2; ++e) {
      const float fg = 1.f / (1.f + expf(-(z[e][0] + bfv)));
      const float ig = 1.f / (1.f + expf(-(z[e][1] + biv)));
      const float gg = tanhf(z[e][2] + bgv);
      const float og = 1.f / (1.f + expf(-(z[e][3] + bov)));
      cr[e] = fg * cr[e] + ig * gg;
      const float h = og * tanhf(cr[e]);
      const int m = bm0 + wid * 8 + fq * 2 + e;
      const size_t off = (size_t)m * HID + j;
      outSl[off] = h;                                        // harness output
      store_bf16_sc(hseq + (size_t)t2 * BHSZ + off, (bf16)h); // consumers
      if (t2 == T_STEPS - 1) cxws[off] = cr[e];              // cx via ws
    }
  };

#define MFMA16(ACC, SLOT, S) do {                                           \
    __builtin_amdgcn_s_setprio(1);                                          \
    _Pragma("unroll")                                                       \
    for (int mf_ = 0; mf_ < 4; ++mf_) {                                     \
      _Pragma("unroll")                                                     \
      for (int nf_ = 0; nf_ < 4; ++nf_)                                     \
        ACC[mf_][nf_] = __builtin_amdgcn_mfma_f32_16x16x32_bf16(            \
            SLOT[mf_], breg[S][nf_], ACC[mf_][nf_], 0, 0, 0);               \
    }                                                                       \
    __builtin_amdgcn_s_setprio(0);                                          \
  } while (0)

#define STEPB(T0, X0, X1, H2, H3, H4, H5, NX0, NX1, W0, W1) do {            \
    const int t_ = (T0);                                                    \
    f32x4 acc[4][4] = {};                                                   \
    VMW(W0);  MFMA16(acc, X0, 0);                                           \
    VMW(W1);  MFMA16(acc, X1, 1);                                           \
    if (wid == 0 && t_ > 0) pollf(t_ - 1);                                  \
    __builtin_amdgcn_s_barrier();  /* h ready; also redu WAR fence */       \
    ldh(t_, 2, H2); SBAR();                                                 \
    ldh(t_, 3, H3); SBAR();                                                 \
    ldh(t_, 4, H4); SBAR();                                                 \
    ldh(t_, 5, H5); SBAR();                                                 \
    VMW(12); MFMA16(acc, H2, 2);                                            \
    VMW(8);  MFMA16(acc, H3, 3);                                            \
    VMW(4);  MFMA16(acc, H4, 4);                                            \
    VMW(0);  MFMA16(acc, H5, 5);                                            \
    finish(t_, acc);                                                        \
    SBAR();                                                                 \
    if (t_ + 1 < T_STEPS) {                                                 \
      ldx(t_ + 1, 0, NX0); SBAR();                                          \
      ldx(t_ + 1, 1, NX1); SBAR();                                          \
      VMW(8);               /* oldest 4 = stores acked; x' in flight */     \
    } else {                                                                \
      VMW(0);                                                               \
    }                                                                       \
    if (lane == 0)                                                          \
      __hip_atomic_store((unsigned char*)(flags64 + (size_t)t_ * 256        \
                                          + mblk * 64 + nblk) + wid,        \
                         (unsigned char)1, __ATOMIC_RELAXED,                \
                         __HIP_MEMORY_SCOPE_AGENT);                         \
  } while (0)

  // prologue: x slices of step 0
  ldx(0, 0, sA); SBAR();
  ldx(0, 1, sB); SBAR();

  STEPB(0, sA, sB, sC, sD, sA, sB, sC, sD, 4, 0);
#pragma unroll 1
  for (int t = 1; t < T_STEPS - 2; t += 2) {
    STEPB(t,     sC, sD, sA, sB, sC, sD, sA, sB, 5, 1);
    STEPB(t + 1, sA, sB, sC, sD, sA, sB, sC, sD, 5, 1);
  }
  STEPB(T_STEPS - 1, sC, sD, sA, sB, sC, sD, sA, sB, 5, 1);

#undef STEPB
#undef MFMA16
}

// ---------------------------------------------------------------------------
// Fallback (small ws): round-5 MODE-1 path verbatim (fp32 A from X / out).
__global__ __launch_bounds__(512, 2)
void lstm_fb(const bf16* __restrict__ Bt,
             const float* __restrict__ X,
             const float* __restrict__ zbF,
             float* __restrict__ outF,
             const float* __restrict__ bf_, const float* __restrict__ bi_,
             const float* __restrict__ bg_, const float* __restrict__ bo_,
             unsigned* __restrict__ flags) {
  __shared__ f32x4 redu[8][16][64];
  const int tid = threadIdx.x, lane = tid & 63, wid = tid >> 6;
  const int bid = blockIdx.x;
  const int xcd = bid & 7, sl = bid >> 3;
  const int nblk = xcd * 8 + (sl & 7);
  const int mblk = sl >> 3;
  const int bm0 = mblk * 64;
  const int bn0 = nblk * 64;
  const int fr = lane & 15, fq = lane >> 4;

  if (tid == 0)
    (void)__hip_atomic_load(flags, __ATOMIC_ACQUIRE, __HIP_MEMORY_SCOPE_AGENT);
  __syncthreads();

  const int j = nblk * 16 + fr;
  const float bfv = bf_[j], biv = bi_[j], bgv = bg_[j], bov = bo_[j];
  float cr[2] = {0.f, 0.f};

  bf16x8 breg[6][4];
#pragma unroll
  for (int s = 0; s < 6; ++s) {
    const int ks = wid + 8 * s;
#pragma unroll
    for (int nf = 0; nf < 4; ++nf)
      breg[s][nf] = *(const bf16x8*)(Bt + (size_t)(bn0 + nf * 16 + fr) * KTOT
                                     + ks * 32 + fq * 8);
  }

  bf16x8 afp[2][4];

  auto poll = [&](int tprev) {
    const unsigned* f = flags + (size_t)tprev * 256 + mblk * 64;
    const unsigned long long tt0 = __builtin_amdgcn_s_memrealtime();
    for (;;) {
      unsigned v = __hip_atomic_load(f + lane, __ATOMIC_RELAXED,
                                     __HIP_MEMORY_SCOPE_AGENT);
      if (__all(v != 0)) break;
      __builtin_amdgcn_s_sleep(2);
      if (__builtin_amdgcn_s_memrealtime() - tt0 > (1ULL << 22)) break;
    }
    asm volatile("" ::: "memory");
    __builtin_amdgcn_sched_barrier(0);
  };

  auto loadA = [&](int t2, int s, int p) __attribute__((always_inline)) {
    const int ks = wid + 8 * s;
    const int k = ks * 32 + fq * 8;
    if (s == 2 && t2 > 0) poll(t2 - 1);
    const float* src; int ld, kk;
    if (s < 2) { src = X + (size_t)t2 * BATCH * DIN; ld = DIN; kk = k; }
    else {
      src = (t2 == 0) ? zbF : outF + (size_t)(t2 - 1) * BHSZ;
      ld = HID; kk = k - 512;
    }
#pragma unroll
    for (int mf = 0; mf < 4; ++mf) {
      const float* q = src + (size_t)(bm0 + mf * 16 + fr) * ld + kk;
      const f32x4 lo = *(const f32x4*)q;
      const f32x4 hi = *(const f32x4*)(q + 4);
      bf16x8 v;
      v[0] = (bf16)lo[0]; v[1] = (bf16)lo[1]; v[2] = (bf16)lo[2]; v[3] = (bf16)lo[3];
      v[4] = (bf16)hi[0]; v[5] = (bf16)hi[1]; v[6] = (bf16)hi[2]; v[7] = (bf16)hi[3];
      afp[p][mf] = v;
    }
  };

  loadA(0, 0, 0);

#pragma unroll 1
  for (int t = 0; t < T_STEPS; ++t) {
    f32x4 acc[4][4] = {};
#pragma unroll
    for (int s = 0; s < 6; ++s) {
      if (s < 5)                loadA(t, s + 1, (s + 1) & 1);
      else if (t + 1 < T_STEPS) loadA(t + 1, 0, 0);
      __builtin_amdgcn_s_setprio(1);
#pragma unroll
      for (int mf = 0; mf < 4; ++mf)
#pragma unroll
        for (int nf = 0; nf < 4; ++nf)
          acc[mf][nf] = __builtin_amdgcn_mfma_f32_16x16x32_bf16(
              afp[s & 1][mf], breg[s][nf], acc[mf][nf], 0, 0, 0);
      __builtin_amdgcn_s_setprio(0);
    }

#pragma unroll
    for (int mf = 0; mf < 4; ++mf)
#pragma unroll
      for (int nf = 0; nf < 4; ++nf)
        redu[wid][mf * 4 + nf][lane] = acc[mf][nf];
    __syncthreads();

    const int fbase = (wid >> 1) * 4;
    const int rh = wid & 1;
    float z[2][4];
#pragma unroll
    for (int e = 0; e < 2; ++e) {
      const int rloc = rh * 8 + fq * 2 + e;
      const int lsel = (rloc >> 2) * 16 + fr;
      const int rc = rloc & 3;
#pragma unroll
      for (int nf = 0; nf < 4; ++nf) {
        float sum = 0.f;
#pragma unroll
        for (int s = 0; s < 8; ++s)
          sum += ((const float*)&redu[s][fbase + nf][lsel])[rc];
        z[e][nf] = sum;
      }
    }

    float* outSl = outF + (size_t)t * BHSZ;
#pragma unroll
    for (int e = 0; e < 2; ++e) {
      const float fg = 1.f / (1.f + expf(-(z[e][0] + bfv)));
      const float ig = 1.f / (1.f + expf(-(z[e][1] + biv)));
      const float gg = tanhf(z[e][2] + bgv);
      const float og = 1.f / (1.f + expf(-(z[e][3] + bov)));
      cr[e] = fg * cr[e] + ig * gg;
      const float h = og * tanhf(cr[e]);
      const int m = bm0 + wid * 8 + fq * 2 + e;
      const size_t off = (size_t)m * HID + j;
      __hip_atomic_store(&outSl[off], h, __ATOMIC_RELAXED,
                         __HIP_MEMORY_SCOPE_AGENT);
      if (t == T_STEPS - 1)
        outF[(size_t)(T_STEPS + 1) * BHSZ + off] = cr[e];
    }
    asm volatile("s_waitcnt vmcnt(0)" ::: "memory");
    __syncthreads();
    if (tid == 0)
      __hip_atomic_store(&flags[(size_t)t * 256 + mblk * 64 + nblk], 1u,
                         __ATOMIC_RELAXED, __HIP_MEMORY_SCOPE_AGENT);
  }
}

// ---------------------------------------------------------------------------
extern "C" void kernel_launch(void* const* d_in, const int* in_sizes, int n_in,
                              void* d_out, int out_size, void* d_ws, size_t ws_size,
                              hipStream_t stream) {
  const float* X   = (const float*)d_in[0];
  const float* Wf  = (const float*)d_in[1];
  const float* bf_ = (const float*)d_in[2];
  const float* Wi  = (const float*)d_in[3];
  const float* bi_ = (const float*)d_in[4];
  const float* Wg  = (const float*)d_in[5];
  const float* bg_ = (const float*)d_in[6];
  const float* Wo  = (const float*)d_in[7];
  const float* bo_ = (const float*)d_in[8];
  float* out = (float*)d_out;

  const size_t WtB   = (size_t)NOUT * KTOT * 2;            // 12.58 MB
  const size_t zBb   = BHSZ * 4;                           // 1 MB zeros
  const size_t flagB = (size_t)T_STEPS * 256 * 8;          // 512 KB (u64)
  const size_t cxB   = BHSZ * 4;                           // 1 MB
  const size_t XbB   = (size_t)T_STEPS * BATCH * DIN * 2;  // 67.1 MB
  const size_t HsB   = (size_t)T_STEPS * BHSZ * 2;         // 134.2 MB

  char* ws = (char*)d_ws;
  bf16*               Wt    = (bf16*)ws;                    ws += WtB;
  float*              zbF   = (float*)(void*)ws;            ws += zBb;
  unsigned long long* fl64  = (unsigned long long*)(void*)ws; ws += flagB;
  float*              cxws  = (float*)(void*)ws;            ws += cxB;

  const bool big = ws_size >= WtB + zBb + flagB + cxB + XbB + HsB + (1u << 20);
  bf16* xbp = nullptr;  bf16* hseq = nullptr;
  if (big) {
    xbp  = (bf16*)ws;   ws += XbB;
    hseq = (bf16*)ws;
  }

  hipMemsetAsync(zbF, 0, zBb + flagB, stream);   // zeros + flag array

  convert_w_kernel<<<dim3(KTOT / 64, NOUT / 64), 256, 0, stream>>>(Wf, Wi, Wg, Wo, Wt);

  if (big) {
    convert_x_kernel<<<dim3(BATCH * DIN / 4 / 256, T_STEPS), 256, 0, stream>>>(X, xbp);
    lstm_v6<<<256, 512, 0, stream>>>(Wt, xbp, hseq, (const bf16*)zbF, out,
                                     bf_, bi_, bg_, bo_, fl64, cxws);
    // cx from ws -> out tail
    hipMemcpyAsync(out + (size_t)(T_STEPS + 1) * BHSZ, cxws,
                   BHSZ * 4, hipMemcpyDeviceToDevice, stream);
  } else {
    lstm_fb<<<256, 512, 0, stream>>>(Wt, X, zbF, out,
                                     bf_, bi_, bg_, bo_, (unsigned*)fl64);
  }

  // hx = outputs[T-1]
  hipMemcpyAsync(out + (size_t)T_STEPS * BHSZ, out + (size_t)(T_STEPS - 1) * BHSZ,
                 BHSZ * 4, hipMemcpyDeviceToDevice, stream);
}